// Round 5
// baseline (147.317 us; speedup 1.0000x reference)
//
#include <hip/hip_runtime.h>
#include <hip/hip_bf16.h>
#include <math.h>

// HGCN decoder, B=512, N=128, D=256, F=16, L=3, c=1 Poincare ball.
// One 1024-thread block per batch (16 waves). sT/sV in LDS with +8 f16 row
// padding (row stride % 32 words == 4 -> uniform 2-way bank access, fully
// additive addressing). Both GEMMs tiled 2x4 per wave to cut LDS A-frag
// traffic 2.6x vs round 3. FP16 MFMA 16x16x32, f32 accumulate.

typedef _Float16 f16;
typedef f16 f16x8 __attribute__((ext_vector_type(8)));
typedef f16 f16x4 __attribute__((ext_vector_type(4)));
typedef f16 f16x2 __attribute__((ext_vector_type(2)));
typedef __fp16 fp16x2_cv __attribute__((ext_vector_type(2)));
typedef float f32x4 __attribute__((ext_vector_type(4)));

#define NB 512
#define NN 128
#define ND 256
#define NF 16
#define NL 3

#define SDT 264   // sT row stride f16: 256+8 -> 528B = 132 words, %32 = 4
#define SDV 136   // sV row stride f16: 128+8 -> 272B =  68 words, %32 = 4

#define EPSV   1e-7f
#define MAXN   0.99999f      // 1 - 1e-5
#define ATHMAX 6.1030340f    // atanh(1 - 1e-5)

__device__ __forceinline__ f16x4 pack4(float a, float b, float c, float d) {
    fp16x2_cv lo = __builtin_amdgcn_cvt_pkrtz(a, b);
    fp16x2_cv hi = __builtin_amdgcn_cvt_pkrtz(c, d);
    f16x2 lo2, hi2;
    __builtin_memcpy(&lo2, &lo, sizeof(lo2));
    __builtin_memcpy(&hi2, &hi, sizeof(hi2));
    return __builtin_shufflevector(lo2, hi2, 0, 1, 2, 3);
}

// One-time: Wt[l][n][k] = W[l][k][n] (f16), WoutT[f][k] = Wout[k][f] (f16).
__global__ void prep_kernel(const float* __restrict__ Ws,
                            const float* __restrict__ Wout,
                            f16* __restrict__ Wt, f16* __restrict__ WoutT) {
    int idx = blockIdx.x * 256 + threadIdx.x;
    if (idx < NL * ND * ND) {
        int l = idx / (ND * ND);
        int r = idx % (ND * ND);
        int n = r >> 8;
        int k = r & 255;
        Wt[idx] = (f16)Ws[l * ND * ND + k * ND + n];
    }
    if (idx < NF * ND) {
        int f = idx >> 8;
        int k = idx & 255;
        WoutT[idx] = (f16)Wout[k * NF + f];
    }
}

__global__ __launch_bounds__(1024, 4)
void hgcn_kernel(const float* __restrict__ x,
                 const float* __restrict__ adj,
                 const float* __restrict__ node_mask,
                 const f16*  __restrict__ Wt,
                 const float* __restrict__ bs,
                 const f16*  __restrict__ WoutT,
                 const float* __restrict__ bout,
                 float* __restrict__ out) {
    __shared__ __align__(16) f16 sT[NN * SDT];    // [node m][feat k] 67.6KB
    __shared__ __align__(16) f16 sV[ND * SDV];    // [feat n][node m] 69.6KB
    __shared__ __align__(16) float sRed[NN * 4];  // per-node 4 partials 2KB

    const int b    = blockIdx.x;
    const int tid  = threadIdx.x;
    const int wave = tid >> 6;   // 0..15
    const int lane = tid & 63;
    const int lg   = lane >> 4;  // 0..3
    const int lc   = lane & 15;

    // GEMM-a role: m-tiles {2*ga_mb,+1}, n-tiles {4*ga_nb..+3}
    const int ga_mb = wave & 3;
    const int ga_nb = wave >> 2;
    // GEMM-b role: i-tiles {2*gb_ip,+1}, n-tiles {4*gb_nq..+3}
    const int gb_ip = wave >> 2;  // 0..3
    const int gb_nq = wave & 3;   // 0..3

    const f32x4 fzero = {0.f, 0.f, 0.f, 0.f};

    // ---------- adj B-fragments for GEMM-b (regs, all 3 layers) ------------
    // U^T[n][i] = sum_j V^T[n][j]*adj[i][j]: B[k=j][col=i] = adj[i0+lc][j].
    f16x8 adjf[2][4];
    {
        const float* adjb = adj + (size_t)b * NN * NN;
        #pragma unroll
        for (int it = 0; it < 2; ++it)
            #pragma unroll
            for (int ks = 0; ks < 4; ++ks) {
                const float4* ap = (const float4*)(adjb + (gb_ip * 32 + it * 16 + lc) * NN + ks * 32 + lg * 8);
                float4 alo = ap[0], ahi = ap[1];
                f16x4 l4 = pack4(alo.x, alo.y, alo.z, alo.w);
                f16x4 h4 = pack4(ahi.x, ahi.y, ahi.z, ahi.w);
                adjf[it][ks] = __builtin_shufflevector(l4, h4, 0, 1, 2, 3, 4, 5, 6, 7);
            }
    }

    // ---------- init: sT = f16(logmap0(proj(x[b]))), 8 rows per wave -------
    {
        const float4* xb = (const float4*)(x + (size_t)b * NN * ND);
        #pragma unroll
        for (int r = 0; r < 8; ++r) {
            int row = wave * 8 + r;
            float4 v = xb[row * 64 + lane];
            float ssq = v.x * v.x + v.y * v.y + v.z * v.z + v.w * v.w;
            #pragma unroll
            for (int d = 1; d < 64; d <<= 1) ssq += __shfl_xor(ssq, d);
            float norm = sqrtf(ssq);
            float sc1 = (norm > MAXN) ? (MAXN / norm) : 1.0f;      // proj
            float hn  = fmaxf(norm * sc1, EPSV);
            float aa  = fminf(hn, MAXN);
            float ath = 0.5f * __logf((1.0f + aa) / (1.0f - aa));  // atanh
            float s   = sc1 * ath / hn;                            // logmap0
            *(f16x4*)&sT[row * SDT + lane * 4] =
                pack4(v.x * s, v.y * s, v.z * s, v.w * s);
        }
    }
    __syncthreads();

    for (int layer = 0; layer < NL; ++layer) {
        const f16* WtL = Wt + layer * ND * ND;

        float bias[4];
        #pragma unroll
        for (int nt = 0; nt < 4; ++nt)
            bias[nt] = bs[layer * ND + (ga_nb * 4 + nt) * 16 + lc];

        // ---- GEMM-a: V[m][n] = T @ W + b. A = sT rows (LDS), B = Wt rows
        // (global/L2, 1-deep register double-buffer). 2 m-tiles x 4 n-tiles.
        f32x4 acc_a[2][4];
        #pragma unroll
        for (int mt = 0; mt < 2; ++mt)
            #pragma unroll
            for (int nt = 0; nt < 4; ++nt) acc_a[mt][nt] = fzero;

        f16x8 bcur[4], bnxt[4];
        #pragma unroll
        for (int nt = 0; nt < 4; ++nt)
            bcur[nt] = *(const f16x8*)(WtL + ((ga_nb * 4 + nt) * 16 + lc) * ND + lg * 8);

        #pragma unroll
        for (int ks = 0; ks < 8; ++ks) {
            if (ks < 7) {
                #pragma unroll
                for (int nt = 0; nt < 4; ++nt)
                    bnxt[nt] = *(const f16x8*)(WtL + ((ga_nb * 4 + nt) * 16 + lc) * ND + (ks + 1) * 32 + lg * 8);
            }
            f16x8 a0 = *(const f16x8*)&sT[(ga_mb * 32 +      lc) * SDT + ks * 32 + lg * 8];
            f16x8 a1 = *(const f16x8*)&sT[(ga_mb * 32 + 16 + lc) * SDT + ks * 32 + lg * 8];
            #pragma unroll
            for (int nt = 0; nt < 4; ++nt) {
                acc_a[0][nt] = __builtin_amdgcn_mfma_f32_16x16x32_f16(a0, bcur[nt], acc_a[0][nt], 0, 0, 0);
                acc_a[1][nt] = __builtin_amdgcn_mfma_f32_16x16x32_f16(a1, bcur[nt], acc_a[1][nt], 0, 0, 0);
            }
            if (ks < 7) {
                #pragma unroll
                for (int nt = 0; nt < 4; ++nt) bcur[nt] = bnxt[nt];
            }
        }
        // epilogue-a: +bias, pack f16x4 (4 consecutive m), store sV[n][m].
        #pragma unroll
        for (int mt = 0; mt < 2; ++mt)
            #pragma unroll
            for (int nt = 0; nt < 4; ++nt) {
                int n  = (ga_nb * 4 + nt) * 16 + lc;
                int m0 = ga_mb * 32 + mt * 16 + lg * 4;
                *(f16x4*)&sV[n * SDV + m0] =
                    pack4(acc_a[mt][nt][0] + bias[nt], acc_a[mt][nt][1] + bias[nt],
                          acc_a[mt][nt][2] + bias[nt], acc_a[mt][nt][3] + bias[nt]);
            }
        __syncthreads();

        // ---- GEMM-b: U^T[n][i]. A = sV rows (LDS), B = adjf (regs).
        f32x4 acc_b[2][4];
        #pragma unroll
        for (int it = 0; it < 2; ++it)
            #pragma unroll
            for (int nt = 0; nt < 4; ++nt) acc_b[it][nt] = fzero;

        #pragma unroll
        for (int ks = 0; ks < 4; ++ks) {
            #pragma unroll
            for (int nt = 0; nt < 4; ++nt) {
                f16x8 afr = *(const f16x8*)&sV[((gb_nq * 4 + nt) * 16 + lc) * SDV + ks * 32 + lg * 8];
                acc_b[0][nt] = __builtin_amdgcn_mfma_f32_16x16x32_f16(afr, adjf[0][ks], acc_b[0][nt], 0, 0, 0);
                acc_b[1][nt] = __builtin_amdgcn_mfma_f32_16x16x32_f16(afr, adjf[1][ks], acc_b[1][nt], 0, 0, 0);
            }
        }

        // ---- epilogue-b: relu + partial node-norm; 4-way sRed exchange.
        float ssq[2] = {0.f, 0.f};
        #pragma unroll
        for (int it = 0; it < 2; ++it)
            #pragma unroll
            for (int nt = 0; nt < 4; ++nt)
                #pragma unroll
                for (int r = 0; r < 4; ++r) {
                    float v = fmaxf(acc_b[it][nt][r], 0.0f);
                    acc_b[it][nt][r] = v;
                    ssq[it] += v * v;
                }
        #pragma unroll
        for (int it = 0; it < 2; ++it) {
            ssq[it] += __shfl_xor(ssq[it], 16);
            ssq[it] += __shfl_xor(ssq[it], 32);
        }
        if (lg == 0) {
            sRed[(gb_ip * 32 +      lc) * 4 + gb_nq] = ssq[0];
            sRed[(gb_ip * 32 + 16 + lc) * 4 + gb_nq] = ssq[1];
        }
        __syncthreads();

        float scale[2];
        #pragma unroll
        for (int it = 0; it < 2; ++it) {
            f32x4 p = *(const f32x4*)&sRed[(gb_ip * 32 + it * 16 + lc) * 4];
            float tot = p[0] + p[1] + p[2] + p[3];
            float nu = sqrtf(tot);
            scale[it] = (nu > ATHMAX) ? (ATHMAX / nu) : 1.0f;
        }
        // fused logmap0(proj(expmap0(u))) = u * min(1, ATHMAX/||u||) -> sT.
        #pragma unroll
        for (int it = 0; it < 2; ++it)
            #pragma unroll
            for (int nt = 0; nt < 4; ++nt) {
                int i  = gb_ip * 32 + it * 16 + lc;
                int k0 = (gb_nq * 4 + nt) * 16 + lg * 4;
                *(f16x4*)&sT[i * SDT + k0] =
                    pack4(acc_b[it][nt][0] * scale[it], acc_b[it][nt][1] * scale[it],
                          acc_b[it][nt][2] * scale[it], acc_b[it][nt][3] * scale[it]);
            }
        __syncthreads();
    }

    // ---------- head: out = (out_tan @ Wout + bout) * node_mask ------------
    if (wave < 8) {
        f32x4 acc = fzero;
        #pragma unroll
        for (int ks = 0; ks < 8; ++ks) {
            f16x8 afr = *(const f16x8*)&sT[(wave * 16 + lc) * SDT + ks * 32 + lg * 8];
            f16x8 bfr = *(const f16x8*)(WoutT + lc * ND + ks * 32 + lg * 8);
            acc = __builtin_amdgcn_mfma_f32_16x16x32_f16(afr, bfr, acc, 0, 0, 0);
        }
        #pragma unroll
        for (int r = 0; r < 4; ++r) {
            int row = wave * 16 + lg * 4 + r;
            float mask = node_mask[b * NN + row];
            out[((size_t)b * NN + row) * NF + lc] = (acc[r] + bout[lc]) * mask;
        }
    }
}

extern "C" void kernel_launch(void* const* d_in, const int* in_sizes, int n_in,
                              void* d_out, int out_size, void* d_ws, size_t ws_size,
                              hipStream_t stream) {
    const float* x    = (const float*)d_in[0];
    const float* adj  = (const float*)d_in[1];
    const float* mask = (const float*)d_in[2];
    const float* Ws   = (const float*)d_in[3];
    const float* bsp  = (const float*)d_in[4];
    const float* Wout = (const float*)d_in[5];
    const float* bout = (const float*)d_in[6];

    f16* Wt    = (f16*)d_ws;                       // 3*256*256 f16 = 384KB
    f16* WoutT = Wt + NL * ND * ND;                // 16*256 f16 = 8KB

    prep_kernel<<<768, 256, 0, stream>>>(Ws, Wout, Wt, WoutT);
    hgcn_kernel<<<NB, 1024, 0, stream>>>(x, adj, mask, Wt, bsp, WoutT, bout,
                                         (float*)d_out);
}

// Round 6
// 78.258 us; speedup vs baseline: 1.8825x; 1.8825x over previous
//
#include <hip/hip_runtime.h>
#include <hip/hip_bf16.h>
#include <math.h>

// HGCN decoder, B=512, N=128, D=256, F=16, L=3, c=1 Poincare ball.
// Round-3 loop structure (1 n-tile/wave GEMM-a with 8x B-frag reuse;
// wave-pair GEMM-b with adj fragments in registers for all 3 layers)
// + round-5 VALU fixes (cvt_pkrtz packing, padded-linear LDS addressing:
// row stride % 32 words == 4 -> uniform bank spread, no swizzle math).
// FP16 MFMA 16x16x32, f32 accumulate. 16 waves / block, 1 block = 1 batch.

typedef _Float16 f16;
typedef f16 f16x8 __attribute__((ext_vector_type(8)));
typedef f16 f16x4 __attribute__((ext_vector_type(4)));
typedef f16 f16x2 __attribute__((ext_vector_type(2)));
typedef __fp16 fp16x2_cv __attribute__((ext_vector_type(2)));
typedef float f32x4 __attribute__((ext_vector_type(4)));

#define NB 512
#define NN 128
#define ND 256
#define NF 16
#define NL 3

#define SDT 264   // sT row stride f16: 528B = 132 words, %32 = 4
#define SDV 136   // sV row stride f16: 272B =  68 words, %32 = 4

#define EPSV   1e-7f
#define MAXN   0.99999f      // 1 - 1e-5
#define ATHMAX 6.1030340f    // atanh(1 - 1e-5)

__device__ __forceinline__ f16x4 pack4(float a, float b, float c, float d) {
    fp16x2_cv lo = __builtin_amdgcn_cvt_pkrtz(a, b);
    fp16x2_cv hi = __builtin_amdgcn_cvt_pkrtz(c, d);
    f16x2 lo2, hi2;
    __builtin_memcpy(&lo2, &lo, sizeof(lo2));
    __builtin_memcpy(&hi2, &hi, sizeof(hi2));
    return __builtin_shufflevector(lo2, hi2, 0, 1, 2, 3);
}

// One-time: Wt[l][n][k] = W[l][k][n] (f16), WoutT[f][k] = Wout[k][f] (f16).
__global__ void prep_kernel(const float* __restrict__ Ws,
                            const float* __restrict__ Wout,
                            f16* __restrict__ Wt, f16* __restrict__ WoutT) {
    int idx = blockIdx.x * 256 + threadIdx.x;
    if (idx < NL * ND * ND) {
        int l = idx / (ND * ND);
        int r = idx % (ND * ND);
        int n = r >> 8;
        int k = r & 255;
        Wt[idx] = (f16)Ws[l * ND * ND + k * ND + n];
    }
    if (idx < NF * ND) {
        int f = idx >> 8;
        int k = idx & 255;
        WoutT[idx] = (f16)Wout[k * NF + f];
    }
}

__global__ __launch_bounds__(1024, 4)
void hgcn_kernel(const float* __restrict__ x,
                 const float* __restrict__ adj,
                 const float* __restrict__ node_mask,
                 const f16*  __restrict__ Wt,
                 const float* __restrict__ bs,
                 const f16*  __restrict__ WoutT,
                 const float* __restrict__ bout,
                 float* __restrict__ out) {
    __shared__ __align__(16) f16 sT[NN * SDT];   // [node m][feat k] 67.6KB
    __shared__ __align__(16) f16 sV[ND * SDV];   // [feat n][node m] 69.6KB
    __shared__ float sRed[16 * 16];              // wave-pair norm exch 1KB

    const int b    = blockIdx.x;
    const int tid  = threadIdx.x;
    const int wave = tid >> 6;   // 0..15
    const int lane = tid & 63;
    const int lg   = lane >> 4;  // 0..3
    const int lc   = lane & 15;

    const f32x4 fzero = {0.f, 0.f, 0.f, 0.f};

    // ---------- adj B-fragments (registers, reused all layers) -------------
    // GEMM-b: U^T[n][i] = sum_j V^T[n][j]*adj[i][j]; B[k=j][col=i], i-tile
    // = wave>>1 (wave pairs share an i-tile and split the n-range).
    f16x8 adjf[4];
    {
        const float* adjb = adj + (size_t)b * NN * NN;
        #pragma unroll
        for (int ks = 0; ks < 4; ++ks) {
            const float4* ap = (const float4*)(adjb + ((wave >> 1) * 16 + lc) * NN + ks * 32 + lg * 8);
            float4 alo = ap[0], ahi = ap[1];
            f16x4 l4 = pack4(alo.x, alo.y, alo.z, alo.w);
            f16x4 h4 = pack4(ahi.x, ahi.y, ahi.z, ahi.w);
            adjf[ks] = __builtin_shufflevector(l4, h4, 0, 1, 2, 3, 4, 5, 6, 7);
        }
    }

    // ---------- init: sT = f16(logmap0(proj(x[b]))), 8 rows per wave -------
    {
        const float4* xb = (const float4*)(x + (size_t)b * NN * ND);
        #pragma unroll
        for (int r = 0; r < 8; ++r) {
            int row = wave * 8 + r;
            float4 v = xb[row * 64 + lane];
            float ssq = v.x * v.x + v.y * v.y + v.z * v.z + v.w * v.w;
            #pragma unroll
            for (int d = 1; d < 64; d <<= 1) ssq += __shfl_xor(ssq, d);
            float norm = sqrtf(ssq);
            float sc1 = (norm > MAXN) ? (MAXN / norm) : 1.0f;      // proj
            float hn  = fmaxf(norm * sc1, EPSV);
            float aa  = fminf(hn, MAXN);
            float ath = 0.5f * __logf((1.0f + aa) / (1.0f - aa));  // atanh
            float s   = sc1 * ath / hn;                            // logmap0
            *(f16x4*)&sT[row * SDT + lane * 4] =
                pack4(v.x * s, v.y * s, v.z * s, v.w * s);
        }
    }
    __syncthreads();

    for (int layer = 0; layer < NL; ++layer) {
        const f16* WtL  = Wt + layer * ND * ND;
        const float bias = bs[layer * ND + wave * 16 + lc];  // n = wave*16+lc

        // ---- GEMM-a: V[m][n] = T @ W + b. Wave owns n-tile = wave, all 8
        // m-tiles. A = sT row m (LDS), B = Wt row n (global/L2, loaded once
        // per ks, reused by 8 MFMAs). D rows m = lg*4+r -> f16x4 sV writes.
        f32x4 acc_a[8];
        #pragma unroll
        for (int t = 0; t < 8; ++t) acc_a[t] = fzero;

        #pragma unroll
        for (int ks = 0; ks < 8; ++ks) {
            f16x8 bfr = *(const f16x8*)(WtL + (wave * 16 + lc) * ND + ks * 32 + lg * 8);
            #pragma unroll
            for (int mt = 0; mt < 8; ++mt) {
                f16x8 afr = *(const f16x8*)&sT[(mt * 16 + lc) * SDT + ks * 32 + lg * 8];
                acc_a[mt] = __builtin_amdgcn_mfma_f32_16x16x32_f16(afr, bfr, acc_a[mt], 0, 0, 0);
            }
        }
        #pragma unroll
        for (int mt = 0; mt < 8; ++mt) {
            int n  = wave * 16 + lc;
            int m0 = mt * 16 + lg * 4;
            *(f16x4*)&sV[n * SDV + m0] =
                pack4(acc_a[mt][0] + bias, acc_a[mt][1] + bias,
                      acc_a[mt][2] + bias, acc_a[mt][3] + bias);
        }
        __syncthreads();

        // ---- GEMM-b: U^T[n][i]. i-tile = wave>>1, n-tiles (wave&1)*8+nt.
        // A = sV row n (LDS), B = adjf (registers).
        f32x4 acc_b[8];
        #pragma unroll
        for (int t = 0; t < 8; ++t) acc_b[t] = fzero;

        #pragma unroll
        for (int ks = 0; ks < 4; ++ks) {
            #pragma unroll
            for (int nt = 0; nt < 8; ++nt) {
                f16x8 afr = *(const f16x8*)&sV[(((wave & 1) * 8 + nt) * 16 + lc) * SDV + ks * 32 + lg * 8];
                acc_b[nt] = __builtin_amdgcn_mfma_f32_16x16x32_f16(afr, adjf[ks], acc_b[nt], 0, 0, 0);
            }
        }

        // ---- epilogue-b: relu + half-node-norm; partner wave^1 has the
        // other n-half -> sRed exchange; fused rescale; write own sT rows.
        float ssq = 0.f;
        #pragma unroll
        for (int t = 0; t < 8; ++t)
            #pragma unroll
            for (int r = 0; r < 4; ++r) {
                float v = fmaxf(acc_b[t][r], 0.0f);
                acc_b[t][r] = v;
                ssq += v * v;
            }
        ssq += __shfl_xor(ssq, 16);   // reduce over lg lanes
        ssq += __shfl_xor(ssq, 32);
        if (lg == 0) sRed[wave * 16 + lc] = ssq;
        __syncthreads();
        float tot = ssq + sRed[(wave ^ 1) * 16 + lc];
        float nu = sqrtf(tot);
        float scale = (nu > ATHMAX) ? (ATHMAX / nu) : 1.0f;

        #pragma unroll
        for (int nt = 0; nt < 8; ++nt) {
            int i  = (wave >> 1) * 16 + lc;
            int k0 = ((wave & 1) * 8 + nt) * 16 + lg * 4;
            *(f16x4*)&sT[i * SDT + k0] =
                pack4(acc_b[nt][0] * scale, acc_b[nt][1] * scale,
                      acc_b[nt][2] * scale, acc_b[nt][3] * scale);
        }
        __syncthreads();
    }

    // ---------- head: out = (out_tan @ Wout + bout) * node_mask ------------
    if (wave < 8) {
        f32x4 acc = fzero;
        #pragma unroll
        for (int ks = 0; ks < 8; ++ks) {
            f16x8 afr = *(const f16x8*)&sT[(wave * 16 + lc) * SDT + ks * 32 + lg * 8];
            f16x8 bfr = *(const f16x8*)(WoutT + lc * ND + ks * 32 + lg * 8);
            acc = __builtin_amdgcn_mfma_f32_16x16x32_f16(afr, bfr, acc, 0, 0, 0);
        }
        #pragma unroll
        for (int r = 0; r < 4; ++r) {
            int row = wave * 16 + lg * 4 + r;
            float mask = node_mask[b * NN + row];
            out[((size_t)b * NN + row) * NF + lc] = (acc[r] + bout[lc]) * mask;
        }
    }
}

extern "C" void kernel_launch(void* const* d_in, const int* in_sizes, int n_in,
                              void* d_out, int out_size, void* d_ws, size_t ws_size,
                              hipStream_t stream) {
    const float* x    = (const float*)d_in[0];
    const float* adj  = (const float*)d_in[1];
    const float* mask = (const float*)d_in[2];
    const float* Ws   = (const float*)d_in[3];
    const float* bsp  = (const float*)d_in[4];
    const float* Wout = (const float*)d_in[5];
    const float* bout = (const float*)d_in[6];

    f16* Wt    = (f16*)d_ws;                       // 3*256*256 f16 = 384KB
    f16* WoutT = Wt + NL * ND * ND;                // 16*256 f16 = 8KB

    prep_kernel<<<768, 256, 0, stream>>>(Ws, Wout, Wt, WoutT);
    hgcn_kernel<<<NB, 1024, 0, stream>>>(x, adj, mask, Wt, bsp, WoutT, bout,
                                         (float*)d_out);
}